// Round 18
// baseline (145.958 us; speedup 1.0000x reference)
//
#include <hip/hip_runtime.h>

#define NDIM 24          // NC*3
#define NCONE 8
#define PGD_ITERS 100
#define BATCH 65536
#define BLOCKT 256       // 4 waves/block, 32 elements per wave
#define EPB 128          // elements per block
#define POW_ITERS 48

typedef _Float16 f16x8  __attribute__((ext_vector_type(8)));
typedef float    f32x16 __attribute__((ext_vector_type(16)));
typedef unsigned u32x4  __attribute__((ext_vector_type(4)));

__device__ __forceinline__ float fast_rsq(float x) { return __builtin_amdgcn_rsqf(x); }

// C-row -> logical component (validated R15/R16: cones lane-local, t first):
//   lane reg r (0..11) <-> C-row (r&3)+8*(r>>2)+4*half; comp = PINV[row].
__device__ const int PINV[32] = {
    0, 8, 9, 1,   4, 16, 17, 5,   10, 11, 2, 12,   18, 19, 6, 20,
    13, 3, 14, 15, 21, 7, 22, 23, 0, 0, 0, 0, 0, 0, 0, 0 };

// k'-slot -> component (-1 = dead; A column zeroed, B don't-care).
// Lane half h's slots hold its OWN 12 comps in l-register order (validated
// R16: B-build needs no cross-lane traffic).
__device__ const int SIG[32] = {
    0, 8, 9, 1, 10, 11, 2, 12,          // slots 0-7  = h0 l[0..7]
    4, 16, 17, 5, 18, 19, 6, 20,        // slots 8-15 = h1 l[0..7]
    13, 3, 14, 15, -1, -1, -1, -1,      // slots 16-19 = h0 l[8..11]
    21, 7, 22, 23, -1, -1, -1, -1 };    // slots 24-27 = h1 l[8..11]

// Branchless SOC projection (algebra verified over all 3 regions + n=0):
//   tn = max3(t, coef, 0); s = clamp(coef*rsq, 0, 1) = med3.
__device__ __forceinline__ void soc_proj(float& t, float& x0, float& x1) {
    float n2   = fmaf(x0, x0, x1 * x1);
    float n2s  = fmaxf(n2, 1e-30f);
    float rsq  = fast_rsq(n2s);
    float n    = n2s * rsq;
    float coef = 0.5f * (t + n);
    float sc   = coef * rsq;
    float tn, s;
    asm("v_max3_f32 %0, %1, %2, 0" : "=v"(tn) : "v"(t),  "v"(coef));
    asm("v_med3_f32 %0, %1, 0, 1.0" : "=v"(s) : "v"(sc));
    t = tn; x0 *= s; x1 *= s;
}

// Residual pack: r = f16(l - (f32)h) written directly into lo/hi half of rw.
#define RES_LO(rw_, w_, l_)                                                    \
    asm("v_fma_mixlo_f16 %0, %1, -1.0, %2 op_sel:[0,0,0] op_sel_hi:[1,0,0]"    \
        : "=v"(rw_) : "v"(w_), "v"(l_))
#define RES_HI(rw_, w_, l_)                                                    \
    asm("v_fma_mixhi_f16 %0, %1, -1.0, %2 op_sel:[1,0,0] op_sel_hi:[1,0,0]"    \
        : "+v"(rw_) : "v"(w_), "v"(l_))

// ---------------------------------------------------------------------------
// Fused kernel, v18 (= v17 + cvt_pkrtz type fix: the builtin returns an
// __fp16 vector, not _Float16 — bit_cast the result straight to unsigned).
//
// R15 118us (MFMA works) -> R16 99us (sigma-slots kill shfl). R16 residue:
// ~150 VALU insts/wave-iter of pack/residual/update/projection plumbing.
// v18 cuts it three ways:
//  1. A-frags hold M = I - step*P; acc init = sq = -step*q. The MFMA output
//     IS y — the 12 per-iter update FMAs vanish. f16(M) is 2x MORE accurate
//     than f16(P) through the update (5e-4 vs step-scaled 5e-3).
//  2. Projection: cndmask chains -> v_max3 / v_med3 (1 inst each).
//  3. Pack: v_cvt_pkrtz (2 comps/inst) + v_fma_mixlo/hi_f16 residuals
//     (fused sub+cvt+pack, 1 inst/comp): 18 insts vs ~60.
// Residual MFMA pair keeps l effectively f32. Zero memory ops in loop.
// ---------------------------------------------------------------------------
__global__ __launch_bounds__(BLOCKT, 2) void pgd_mfma(const float* __restrict__ P,
                                                      const float* __restrict__ q,
                                                      float* __restrict__ out) {
    __shared__ __align__(16) float sP[NDIM * NDIM];   // fp32 P (pow-iter + frags)
    __shared__ float sQ[EPB * (NDIM + 1)];            // q/out slab, stride 25

    const int tid   = threadIdx.x;
    const int lane  = tid & 63;
    const int wv    = tid >> 6;
    const int half  = lane >> 5;
    const int col   = lane & 31;
    const int ebase = blockIdx.x * EPB;
    const int eloc  = wv * 32 + col;

    for (int i = tid; i < NDIM * NDIM; i += BLOCKT)
        sP[i] = P[i];
    for (int idx = tid; idx < EPB * NDIM; idx += BLOCKT) {
        int r = idx / NDIM, c = idx - r * NDIM;
        sQ[r * (NDIM + 1) + c] = q[ebase * NDIM + idx];
    }
    __syncthreads();

    // --- step = 1/lambda_max(P): per-wave power iteration + Rayleigh ---
    // (zero inter-block state — R2's graph-replay divergence lesson)
    float step;
    {
        float p[NDIM];
#pragma unroll
        for (int j = 0; j < NDIM; ++j)
            p[j] = (lane < NDIM) ? sP[lane * NDIM + j] : 0.0f;
        float v = (lane < NDIM) ? (1.0f + 0.01f * (float)lane) : 0.0f;

        for (int it = 0; it < POW_ITERS; ++it) {
            float w = 0.0f;
#pragma unroll
            for (int j = 0; j < NDIM; ++j)
                w = fmaf(p[j], __shfl(v, j, 64), w);
            float n2 = w * w;
#pragma unroll
            for (int off = 32; off >= 1; off >>= 1)
                n2 += __shfl_xor(n2, off, 64);
            v = w * rsqrtf(n2);
        }
        float w = 0.0f;
#pragma unroll
        for (int j = 0; j < NDIM; ++j)
            w = fmaf(p[j], __shfl(v, j, 64), w);
        float num = v * w;
        float den = v * v;
#pragma unroll
        for (int off = 32; off >= 1; off >>= 1) {
            num += __shfl_xor(num, off, 64);
            den += __shfl_xor(den, off, 64);
        }
        step = den / num;
    }

    // --- loop-invariant A-frags: A[m][k'] = M[PINV[m]][SIG[k']], f16,
    //     where M = I - step*P (the PGD update folded into the matrix) ---
    f16x8 a0, a1;
    {
        const int m  = col;
        const int cm = PINV[m];
#pragma unroll
        for (int j = 0; j < 8; ++j) {
            int s0 = 8 * half + j;            // MFMA1 slots (all live)
            int c0 = SIG[s0];
            float v0 = (cm == c0 ? 1.0f : 0.0f) - step * sP[cm * NDIM + c0];
            a0[j] = (_Float16)((m < 24) ? v0 : 0.0f);
            int s1 = 16 + 8 * half + j;       // MFMA2 slots (may be dead)
            int c1 = SIG[s1];
            float v1 = (c1 >= 0)
                ? (cm == c1 ? 1.0f : 0.0f) - step * sP[cm * NDIM + c1] : 0.0f;
            a1[j] = (_Float16)((m < 24) ? v1 : 0.0f);
        }
    }

    // --- sq = -step*q in C-layout (accumulator init) ---
    f32x16 qv;
#pragma unroll
    for (int r = 0; r < 16; ++r) qv[r] = 0.0f;
#pragma unroll
    for (int r = 0; r < 12; ++r) {
        int row = (r & 3) + 8 * (r >> 2) + 4 * half;
        qv[r] = -step * sQ[eloc * (NDIM + 1) + PINV[row]];
    }

    float l[12];
#pragma unroll
    for (int r = 0; r < 12; ++r) l[r] = 0.0f;

#pragma clang loop unroll(disable)
    for (int it = 0; it < PGD_ITERS; ++it) {
        // pack own l: main via cvt_pkrtz, residual via fma_mixlo/hi
        unsigned w[6], rw[6];
#pragma unroll
        for (int p = 0; p < 6; ++p) {
            w[p] = __builtin_bit_cast(
                unsigned, __builtin_amdgcn_cvt_pkrtz(l[2 * p], l[2 * p + 1]));
            RES_LO(rw[p], w[p], l[2 * p]);
            RES_HI(rw[p], w[p], l[2 * p + 1]);
        }
        u32x4 b0u, b1u, b0ru, b1ru;
        b0u.x  = w[0];  b0u.y  = w[1];  b0u.z  = w[2];  b0u.w  = w[3];
        b1u.x  = w[4];  b1u.y  = w[5];  b1u.z  = w[4];  b1u.w  = w[5];   // hi: dead
        b0ru.x = rw[0]; b0ru.y = rw[1]; b0ru.z = rw[2]; b0ru.w = rw[3];
        b1ru.x = rw[4]; b1ru.y = rw[5]; b1ru.z = rw[4]; b1ru.w = rw[5];  // hi: dead
        f16x8 b0  = __builtin_bit_cast(f16x8, b0u);
        f16x8 b1  = __builtin_bit_cast(f16x8, b1u);
        f16x8 b0r = __builtin_bit_cast(f16x8, b0ru);
        f16x8 b1r = __builtin_bit_cast(f16x8, b1ru);

        // y = M.(l_hi + l_lo) + sq — the MFMA output IS the pre-projection y
        f32x16 acc = qv;
        acc = __builtin_amdgcn_mfma_f32_32x32x16_f16(a0, b0,  acc, 0, 0, 0);
        acc = __builtin_amdgcn_mfma_f32_32x32x16_f16(a1, b1,  acc, 0, 0, 0);
        acc = __builtin_amdgcn_mfma_f32_32x32x16_f16(a0, b0r, acc, 0, 0, 0);
        acc = __builtin_amdgcn_mfma_f32_32x32x16_f16(a1, b1r, acc, 0, 0, 0);

        // project (cones lane-local at regs 3c..3c+2)
#pragma unroll
        for (int c = 0; c < 4; ++c) {
            float t  = acc[3 * c];
            float x0 = acc[3 * c + 1];
            float x1 = acc[3 * c + 2];
            soc_proj(t, x0, x1);
            l[3 * c] = t; l[3 * c + 1] = x0; l[3 * c + 2] = x1;
        }
    }

    // --- write back through sQ (disjoint comps per lane-pair) ---
#pragma unroll
    for (int r = 0; r < 12; ++r) {
        int row = (r & 3) + 8 * (r >> 2) + 4 * half;
        sQ[eloc * (NDIM + 1) + PINV[row]] = l[r];
    }
    __syncthreads();
    for (int idx = tid; idx < EPB * NDIM; idx += BLOCKT) {
        int r = idx / NDIM, c = idx - r * NDIM;
        out[ebase * NDIM + idx] = sQ[r * (NDIM + 1) + c];
    }
}

extern "C" void kernel_launch(void* const* d_in, const int* in_sizes, int n_in,
                              void* d_out, int out_size, void* d_ws, size_t ws_size,
                              hipStream_t stream) {
    const float* P = (const float*)d_in[0];   // (1, 24, 24) fp32
    const float* q = (const float*)d_in[1];   // (65536, 24, 1) fp32
    float* out     = (float*)d_out;           // (65536, 24) fp32
    (void)d_ws; (void)ws_size;

    pgd_mfma<<<BATCH / EPB, BLOCKT, 0, stream>>>(P, q, out);
}

// Round 19
// 133.281 us; speedup vs baseline: 1.0951x; 1.0951x over previous
//
#include <hip/hip_runtime.h>

#define NDIM 24          // NC*3
#define NCONE 8
#define PGD_ITERS 100
#define BATCH 65536
#define BLOCKT 256       // 4 waves/block, 32 elements per wave
#define EPB 128          // elements per block
#define POW_ITERS 48

typedef _Float16 f16x8  __attribute__((ext_vector_type(8)));
typedef float    f32x16 __attribute__((ext_vector_type(16)));
typedef unsigned u32x4  __attribute__((ext_vector_type(4)));

__device__ __forceinline__ float fast_rsq(float x) { return __builtin_amdgcn_rsqf(x); }

// C-row -> logical component (validated R15-R18: cones lane-local, t first):
//   lane reg r (0..11) <-> C-row (r&3)+8*(r>>2)+4*half; comp = PINV[row].
__device__ const int PINV[32] = {
    0, 8, 9, 1,   4, 16, 17, 5,   10, 11, 2, 12,   18, 19, 6, 20,
    13, 3, 14, 15, 21, 7, 22, 23, 0, 0, 0, 0, 0, 0, 0, 0 };

// k'-slot -> component (-1 = dead; A column zeroed, B don't-care).
// Lane half h's slots hold its OWN 12 comps in l-register order (validated
// R16: B-build needs no cross-lane traffic).
__device__ const int SIG[32] = {
    0, 8, 9, 1, 10, 11, 2, 12,          // slots 0-7  = h0 l[0..7]
    4, 16, 17, 5, 18, 19, 6, 20,        // slots 8-15 = h1 l[0..7]
    13, 3, 14, 15, -1, -1, -1, -1,      // slots 16-19 = h0 l[8..11]
    21, 7, 22, 23, -1, -1, -1, -1 };    // slots 24-27 = h1 l[8..11]

// Branchless SOC projection (validated R18: absmax 0.03125):
//   tn = max3(t, coef, 0); s = clamp(coef*rsq, 0, 1) = med3.
__device__ __forceinline__ void soc_proj(float& t, float& x0, float& x1) {
    float n2   = fmaf(x0, x0, x1 * x1);
    float n2s  = fmaxf(n2, 1e-30f);
    float rsq  = fast_rsq(n2s);
    float n    = n2s * rsq;
    float coef = 0.5f * (t + n);
    float sc   = coef * rsq;
    float tn, s;
    asm("v_max3_f32 %0, %1, %2, 0" : "=v"(tn) : "v"(t),  "v"(coef));
    asm("v_med3_f32 %0, %1, 0, 1.0" : "=v"(s) : "v"(sc));
    t = tn; x0 *= s; x1 *= s;
}

// Residual pack: r = f16(l - (f32)h) written directly into lo/hi half of rw.
#define RES_LO(rw_, w_, l_)                                                    \
    asm("v_fma_mixlo_f16 %0, %1, -1.0, %2 op_sel:[0,0,0] op_sel_hi:[1,0,0]"    \
        : "=v"(rw_) : "v"(w_), "v"(l_))
#define RES_HI(rw_, w_, l_)                                                    \
    asm("v_fma_mixhi_f16 %0, %1, -1.0, %2 op_sel:[1,0,0] op_sel_hi:[1,0,0]"    \
        : "+v"(rw_) : "v"(w_), "v"(l_))

// ---------------------------------------------------------------------------
// Fused kernel, v19 — split MFMA chains.
//
// R16->R18: cutting ~70 VALU insts/wave-iter changed NOTHING (98.6us both).
// Calibrated counters (VALUBusy reads ~2x real on gfx950 via gfx94x formula)
// say the wall is ~80% dependency stall at 2 waves/SIMD: the serial 4-MFMA
// accumulator chain (main+residual both folded into one acc) pays full
// dependent-result latency 4x, and nothing fills it.
// v19: main and residual passes get INDEPENDENT accumulator chains —
//   accA = MFMA(a1,b1, MFMA(a0,b0, qv)),  accB = MFMA(a1,b1r, MFMA(a0,b0r, 0))
// — overlap in hardware; y = accA + accB (12 adds) feeds projection.
// Chain 4 MFMA -> 2 MFMA + 1 add; acc=qv copy eliminated (D != C legal).
// ---------------------------------------------------------------------------
__global__ __launch_bounds__(BLOCKT, 2) void pgd_mfma(const float* __restrict__ P,
                                                      const float* __restrict__ q,
                                                      float* __restrict__ out) {
    __shared__ __align__(16) float sP[NDIM * NDIM];   // fp32 P (pow-iter + frags)
    __shared__ float sQ[EPB * (NDIM + 1)];            // q/out slab, stride 25

    const int tid   = threadIdx.x;
    const int lane  = tid & 63;
    const int wv    = tid >> 6;
    const int half  = lane >> 5;
    const int col   = lane & 31;
    const int ebase = blockIdx.x * EPB;
    const int eloc  = wv * 32 + col;

    for (int i = tid; i < NDIM * NDIM; i += BLOCKT)
        sP[i] = P[i];
    for (int idx = tid; idx < EPB * NDIM; idx += BLOCKT) {
        int r = idx / NDIM, c = idx - r * NDIM;
        sQ[r * (NDIM + 1) + c] = q[ebase * NDIM + idx];
    }
    __syncthreads();

    // --- step = 1/lambda_max(P): per-wave power iteration + Rayleigh ---
    // (zero inter-block state — R2's graph-replay divergence lesson)
    float step;
    {
        float p[NDIM];
#pragma unroll
        for (int j = 0; j < NDIM; ++j)
            p[j] = (lane < NDIM) ? sP[lane * NDIM + j] : 0.0f;
        float v = (lane < NDIM) ? (1.0f + 0.01f * (float)lane) : 0.0f;

        for (int it = 0; it < POW_ITERS; ++it) {
            float w = 0.0f;
#pragma unroll
            for (int j = 0; j < NDIM; ++j)
                w = fmaf(p[j], __shfl(v, j, 64), w);
            float n2 = w * w;
#pragma unroll
            for (int off = 32; off >= 1; off >>= 1)
                n2 += __shfl_xor(n2, off, 64);
            v = w * rsqrtf(n2);
        }
        float w = 0.0f;
#pragma unroll
        for (int j = 0; j < NDIM; ++j)
            w = fmaf(p[j], __shfl(v, j, 64), w);
        float num = v * w;
        float den = v * v;
#pragma unroll
        for (int off = 32; off >= 1; off >>= 1) {
            num += __shfl_xor(num, off, 64);
            den += __shfl_xor(den, off, 64);
        }
        step = den / num;
    }

    // --- loop-invariant A-frags: A[m][k'] = M[PINV[m]][SIG[k']], f16,
    //     where M = I - step*P (validated R18) ---
    f16x8 a0, a1;
    {
        const int m  = col;
        const int cm = PINV[m];
#pragma unroll
        for (int j = 0; j < 8; ++j) {
            int s0 = 8 * half + j;            // MFMA1 slots (all live)
            int c0 = SIG[s0];
            float v0 = (cm == c0 ? 1.0f : 0.0f) - step * sP[cm * NDIM + c0];
            a0[j] = (_Float16)((m < 24) ? v0 : 0.0f);
            int s1 = 16 + 8 * half + j;       // MFMA2 slots (may be dead)
            int c1 = SIG[s1];
            float v1 = (c1 >= 0)
                ? (cm == c1 ? 1.0f : 0.0f) - step * sP[cm * NDIM + c1] : 0.0f;
            a1[j] = (_Float16)((m < 24) ? v1 : 0.0f);
        }
    }

    // --- sq = -step*q in C-layout (accumulator init); zero C for residual ---
    f32x16 qv, zv;
#pragma unroll
    for (int r = 0; r < 16; ++r) { qv[r] = 0.0f; zv[r] = 0.0f; }
#pragma unroll
    for (int r = 0; r < 12; ++r) {
        int row = (r & 3) + 8 * (r >> 2) + 4 * half;
        qv[r] = -step * sQ[eloc * (NDIM + 1) + PINV[row]];
    }

    float l[12];
#pragma unroll
    for (int r = 0; r < 12; ++r) l[r] = 0.0f;

#pragma clang loop unroll(disable)
    for (int it = 0; it < PGD_ITERS; ++it) {
        // pack own l: main via cvt_pkrtz, residual via fma_mixlo/hi
        unsigned w[6], rw[6];
#pragma unroll
        for (int p = 0; p < 6; ++p) {
            w[p] = __builtin_bit_cast(
                unsigned, __builtin_amdgcn_cvt_pkrtz(l[2 * p], l[2 * p + 1]));
            RES_LO(rw[p], w[p], l[2 * p]);
            RES_HI(rw[p], w[p], l[2 * p + 1]);
        }
        u32x4 b0u, b1u, b0ru, b1ru;
        b0u.x  = w[0];  b0u.y  = w[1];  b0u.z  = w[2];  b0u.w  = w[3];
        b1u.x  = w[4];  b1u.y  = w[5];  b1u.z  = w[4];  b1u.w  = w[5];   // hi: dead
        b0ru.x = rw[0]; b0ru.y = rw[1]; b0ru.z = rw[2]; b0ru.w = rw[3];
        b1ru.x = rw[4]; b1ru.y = rw[5]; b1ru.z = rw[4]; b1ru.w = rw[5];  // hi: dead
        f16x8 b0  = __builtin_bit_cast(f16x8, b0u);
        f16x8 b1  = __builtin_bit_cast(f16x8, b1u);
        f16x8 b0r = __builtin_bit_cast(f16x8, b0ru);
        f16x8 b1r = __builtin_bit_cast(f16x8, b1ru);

        // Two INDEPENDENT 2-deep MFMA chains (main w/ qv, residual w/ zero)
        f32x16 accA = __builtin_amdgcn_mfma_f32_32x32x16_f16(a0, b0,  qv, 0, 0, 0);
        f32x16 accB = __builtin_amdgcn_mfma_f32_32x32x16_f16(a0, b0r, zv, 0, 0, 0);
        accA = __builtin_amdgcn_mfma_f32_32x32x16_f16(a1, b1,  accA, 0, 0, 0);
        accB = __builtin_amdgcn_mfma_f32_32x32x16_f16(a1, b1r, accB, 0, 0, 0);

        // y = accA + accB ; project (cones lane-local at regs 3c..3c+2)
#pragma unroll
        for (int c = 0; c < 4; ++c) {
            float t  = accA[3 * c]     + accB[3 * c];
            float x0 = accA[3 * c + 1] + accB[3 * c + 1];
            float x1 = accA[3 * c + 2] + accB[3 * c + 2];
            soc_proj(t, x0, x1);
            l[3 * c] = t; l[3 * c + 1] = x0; l[3 * c + 2] = x1;
        }
    }

    // --- write back through sQ (disjoint comps per lane-pair) ---
#pragma unroll
    for (int r = 0; r < 12; ++r) {
        int row = (r & 3) + 8 * (r >> 2) + 4 * half;
        sQ[eloc * (NDIM + 1) + PINV[row]] = l[r];
    }
    __syncthreads();
    for (int idx = tid; idx < EPB * NDIM; idx += BLOCKT) {
        int r = idx / NDIM, c = idx - r * NDIM;
        out[ebase * NDIM + idx] = sQ[r * (NDIM + 1) + c];
    }
}

extern "C" void kernel_launch(void* const* d_in, const int* in_sizes, int n_in,
                              void* d_out, int out_size, void* d_ws, size_t ws_size,
                              hipStream_t stream) {
    const float* P = (const float*)d_in[0];   // (1, 24, 24) fp32
    const float* q = (const float*)d_in[1];   // (65536, 24, 1) fp32
    float* out     = (float*)d_out;           // (65536, 24) fp32
    (void)d_ws; (void)ws_size;

    pgd_mfma<<<BATCH / EPB, BLOCKT, 0, stream>>>(P, q, out);
}